// Round 1
// baseline (706.331 us; speedup 1.0000x reference)
//
#include <hip/hip_runtime.h>
#include <math.h>

#define NBATCH 2
#define LQ     19560
#define LEN    19560
#define NQ     (NBATCH * LQ)      // 39120
#define DMODEL 256
#define NHEADS 8
#define HDIM   32
#define NLEV   4
#define NPTS   4
#define LDQS   384                // QS row stride: [0..255]=offsets, [256..383]=logits/aw

typedef __bf16 bf16x8 __attribute__((ext_vector_type(8)));
typedef float  f32x4  __attribute__((ext_vector_type(4)));
typedef float  f32x2  __attribute__((ext_vector_type(2)));

__device__ inline float bf2f(unsigned short u) {
    return __uint_as_float(((unsigned int)u) << 16);
}
__device__ inline unsigned short f2bf(float f) {
    unsigned int u = __float_as_uint(f);
    u += 0x7FFFu + ((u >> 16) & 1u);     // RNE
    return (unsigned short)(u >> 16);
}
// two bf16 packed in a dword -> two exact f32 (lo = u<<16, hi = u & 0xFFFF0000)
__device__ inline f32x2 bfpair(unsigned int u) {
    f32x2 r;
    r.x = __uint_as_float(u << 16);
    r.y = __uint_as_float(u & 0xFFFF0000u);
    return r;
}

// ---------------------------------------------------------------------------
// Batched bf16 MFMA GEMM: C_z = A_z @ Bt^T (+bias), z = blockIdx.z
// A: fp32 (a_bf16=0, converted in staging) or bf16 (a_bf16=1), row stride lda.
// Bt: bf16 [N][K] row stride K. 128x128 tile, BK=64, 4 waves, 4x4 16x16x32 MFMA.
// mode 0: store fp32 at C[row*ldc+col]
// mode 2: store bf16 head-major scatter (n, h, pos, d)  [value tensor]
// ---------------------------------------------------------------------------
#define LDK 72

__global__ __launch_bounds__(256) void gemm_multi(
    const void* __restrict__ A0, const void* __restrict__ A1,
    const unsigned short* __restrict__ Bt, const float* __restrict__ bias,
    void* __restrict__ C0, void* __restrict__ C1,
    int M, int K, int lda, int N, int ldc, int a_bf16, int mode)
{
    __shared__ unsigned short As[128 * LDK];
    __shared__ unsigned short Bs[128 * LDK];

    const int z = blockIdx.z;
    const void* A = z ? A1 : A0;
    void* Cv = z ? C1 : C0;

    const int tid  = threadIdx.x;
    const int wave = tid >> 6, lane = tid & 63;
    const int wm = wave >> 1, wn = wave & 1;
    const int m0 = blockIdx.y * 128, n0 = blockIdx.x * 128;
    const int lr = lane & 15, quad = lane >> 4;

    const f32x4 zero = {0.f, 0.f, 0.f, 0.f};
    f32x4 acc[4][4];
    #pragma unroll
    for (int i = 0; i < 4; i++)
        #pragma unroll
        for (int j = 0; j < 4; j++) acc[i][j] = zero;

    for (int t = 0; t < K; t += 64) {
        #pragma unroll
        for (int i = 0; i < 4; i++) {
            int v = tid + i * 256;
            int r = v >> 3, c = v & 7;
            int row = m0 + r;
            uint4 d = make_uint4(0, 0, 0, 0);
            if (row < M) {
                if (a_bf16) {
                    d = *(const uint4*)&((const unsigned short*)A)[(size_t)row * lda + t + c * 8];
                } else {
                    const float* ap = &((const float*)A)[(size_t)row * lda + t + c * 8];
                    float4 x = *(const float4*)ap;
                    float4 y = *(const float4*)(ap + 4);
                    union { uint4 u; unsigned short s[8]; } tmp;
                    tmp.s[0] = f2bf(x.x); tmp.s[1] = f2bf(x.y);
                    tmp.s[2] = f2bf(x.z); tmp.s[3] = f2bf(x.w);
                    tmp.s[4] = f2bf(y.x); tmp.s[5] = f2bf(y.y);
                    tmp.s[6] = f2bf(y.z); tmp.s[7] = f2bf(y.w);
                    d = tmp.u;
                }
            }
            *(uint4*)&As[r * LDK + c * 8] = d;
        }
        #pragma unroll
        for (int i = 0; i < 4; i++) {
            int v = tid + i * 256;
            int r = v >> 3, c = v & 7;
            uint4 d = make_uint4(0, 0, 0, 0);
            if (n0 + r < N) d = *(const uint4*)&Bt[(size_t)(n0 + r) * K + t + c * 8];
            *(uint4*)&Bs[r * LDK + c * 8] = d;
        }
        __syncthreads();

        #pragma unroll
        for (int kk = 0; kk < 2; kk++) {
            bf16x8 af[4], bff[4];
            #pragma unroll
            for (int mi = 0; mi < 4; mi++)
                af[mi] = *(const bf16x8*)&As[(wm * 64 + mi * 16 + lr) * LDK + kk * 32 + quad * 8];
            #pragma unroll
            for (int ni = 0; ni < 4; ni++)
                bff[ni] = *(const bf16x8*)&Bs[(wn * 64 + ni * 16 + lr) * LDK + kk * 32 + quad * 8];
            #pragma unroll
            for (int mi = 0; mi < 4; mi++)
                #pragma unroll
                for (int ni = 0; ni < 4; ni++)
                    acc[mi][ni] = __builtin_amdgcn_mfma_f32_16x16x32_bf16(
                        af[mi], bff[ni], acc[mi][ni], 0, 0, 0);
        }
        __syncthreads();
    }

    float* Cf = (float*)Cv;
    unsigned short* Cb = (unsigned short*)Cv;
    #pragma unroll
    for (int mi = 0; mi < 4; mi++) {
        #pragma unroll
        for (int reg = 0; reg < 4; reg++) {
            int row = m0 + wm * 64 + mi * 16 + quad * 4 + reg;
            if (row >= M) continue;
            #pragma unroll
            for (int ni = 0; ni < 4; ni++) {
                int col = n0 + wn * 64 + ni * 16 + lr;
                float v = acc[mi][ni][reg];
                if (bias) v += bias[col];
                if (mode == 0) {
                    Cf[(size_t)row * ldc + col] = v;
                } else {
                    int n = row >= LQ ? 1 : 0;
                    int pos = row - n * LQ;
                    int h = col >> 5, d = col & 31;
                    Cb[((size_t)(n * NHEADS + h) * LEN + pos) * HDIM + d] = f2bf(v);
                }
            }
        }
    }
}

// ---------------------------------------------------------------------------
// Weight prep: Wvt[n][k]=bf16(Wv[k][n]); Wsoawt[n][k]: n<256 from W_so, else W_aw.
// bsoaw = [b_so | b_aw] fp32(384).
// ---------------------------------------------------------------------------
__global__ __launch_bounds__(256) void prep_weights(
    const float* __restrict__ Wv, const float* __restrict__ Wso,
    const float* __restrict__ Waw, const float* __restrict__ bso,
    const float* __restrict__ baw, unsigned short* __restrict__ Wvt,
    unsigned short* __restrict__ Wsoawt, float* __restrict__ bsoaw)
{
    int o = blockIdx.x * 256 + threadIdx.x;
    if (o < 65536) {
        int n = o >> 8, k = o & 255;
        Wvt[o] = f2bf(Wv[(size_t)k * 256 + n]);
    } else if (o < 65536 + 98304) {
        int p = o - 65536;
        int n = p >> 8, k = p & 255;
        float v = (n < 256) ? Wso[(size_t)k * 256 + n] : Waw[(size_t)k * 128 + (n - 256)];
        Wsoawt[p] = f2bf(v);
    }
    if (o < 384) bsoaw[o] = (o < 256) ? bso[o] : baw[o - 256];
}

// ---------------------------------------------------------------------------
// Fused tail weights, concatenated K=512: Wfcat[n][k] = bf16((Wo@Wagg0)[k][n]),
// Wfcat[n][256+k] = bf16((Wo@Wagg1)[k][n]); bf = b_o@(Wagg0+Wagg1)+b_agg.
// ---------------------------------------------------------------------------
__global__ __launch_bounds__(256) void fuse_weights(
    const float* __restrict__ Wo, const float* __restrict__ Wagg,
    const float* __restrict__ bo, const float* __restrict__ bagg,
    unsigned short* __restrict__ Wfcat, float* __restrict__ bf)
{
    int n = threadIdx.x;
    int k = blockIdx.x;
    float s0 = 0.f, s1 = 0.f;
    for (int j = 0; j < 256; j++) {
        float w = Wo[k * 256 + j];
        s0 += w * Wagg[j * 256 + n];
        s1 += w * Wagg[(256 + j) * 256 + n];
    }
    Wfcat[(size_t)n * 512 + k]       = f2bf(s0);
    Wfcat[(size_t)n * 512 + 256 + k] = f2bf(s1);
    if (k == 0) {
        float b = bagg[n];
        for (int j = 0; j < 256; j++)
            b += bo[j] * (Wagg[j * 256 + n] + Wagg[(256 + j) * 256 + n]);
        bf[n] = b;
    }
}

// ---------------------------------------------------------------------------
// Joint softmax over 32 logits per (n,q,h): QS cols [256..383], in-place
// ---------------------------------------------------------------------------
__global__ __launch_bounds__(256) void joint_softmax(float* __restrict__ QS0,
                                                     float* __restrict__ QS1)
{
    int r = blockIdx.x * 256 + threadIdx.x;
    if (r >= NQ * NHEADS) return;
    int nq = r >> 3, h = r & 7;
    float* p0 = QS0 + (size_t)nq * LDQS + 256 + h * 16;
    float* p1 = QS1 + (size_t)nq * LDQS + 256 + h * 16;
    float v[32];
    #pragma unroll
    for (int i = 0; i < 16; i++) { v[i] = p0[i]; v[16 + i] = p1[i]; }
    float m = v[0];
    #pragma unroll
    for (int i = 1; i < 32; i++) m = fmaxf(m, v[i]);
    float s = 0.f;
    #pragma unroll
    for (int i = 0; i < 32; i++) { v[i] = expf(v[i] - m); s += v[i]; }
    float inv = 1.0f / s;
    #pragma unroll
    for (int i = 0; i < 16; i++) { p0[i] = v[i] * inv; p1[i] = v[16 + i] * inv; }
}

// ---------------------------------------------------------------------------
// Merged deformable sampling (both iters), v2:
//  - grid: b = (((it*2 + n)*CHUNKS + chunk) << 3) | h  -> it,n,h block-uniform,
//    b&7 == h preserved for XCD L2 affinity of the per-(n,h) value slab.
//  - 128 queries/block, 2 lanes/query, lane owns 16 dims (halves the 4-way
//    replicated coord/weight math of v1).
//  - division-free coords: x = ref*W - 0.5 + off  (the /W *W round-trip
//    cancels; removes 2 full-precision fdivs per point).
//  - branchless corners: clamp coords, zero OOB corner *weights* via cndmask;
//    all 4 loads unconditional 32-bit-offset saddr form.
//  - packed f32x2 accumulate (v_pk_fma_f32) on bf16 pairs.
// ---------------------------------------------------------------------------
#define QCHUNK 128
#define CHUNKS ((LQ + QCHUNK - 1) / QCHUNK)   // 153

__global__ __launch_bounds__(256) void ms_sample(
    const unsigned short* __restrict__ V0, const unsigned short* __restrict__ V1,
    const float* __restrict__ QS0, const float* __restrict__ QS1,
    const float* __restrict__ refp, unsigned short* __restrict__ Ocat)
{
    const int b = blockIdx.x;
    const int h = b & 7;
    const int rest = b >> 3;               // (it*2+n)*CHUNKS + chunk
    const int chunk = rest % CHUNKS;
    const int inn   = rest / CHUNKS;       // it*2 + n
    const int n  = inn & 1;
    const int it = inn >> 1;

    const int tid = threadIdx.x;
    const int ql  = tid >> 1;              // 0..127
    const int dl  = (tid & 1) << 4;        // element 0 or 16
    const int q   = chunk * QCHUNK + ql;   // within batch
    if (q >= LQ) return;
    const int nq  = n * LQ + q;

    const unsigned short* __restrict__ val = it ? V1 : V0;
    const float* __restrict__ QS = it ? QS1 : QS0;
    // block-uniform slab base -> SGPR base, 32-bit unsigned element offsets
    const unsigned short* __restrict__ vb2 =
        val + (size_t)(n * NHEADS + h) * LEN * HDIM;

    const int Hs[4] = {92, 46, 23, 12};
    const int Ws[4] = {160, 80, 40, 20};
    const int Ss[4] = {0, 14720, 18400, 19320};

    const float* prow = QS + (size_t)nq * LDQS;
    const float* po = prow + (h << 5);            // this head's 32 offset floats
    const float* pa = prow + 256 + (h << 4);      // this head's 16 attn weights
    const float4 rp01 = *(const float4*)(refp + (size_t)nq * 8);
    const float4 rp23 = *(const float4*)(refp + (size_t)nq * 8 + 4);
    const float rxs[4] = {rp01.x, rp01.z, rp23.x, rp23.z};
    const float rys[4] = {rp01.y, rp01.w, rp23.y, rp23.w};

    f32x2 acc[8];
    #pragma unroll
    for (int i = 0; i < 8; i++) acc[i] = (f32x2){0.f, 0.f};

    auto corner = [&](unsigned int eo, float w) {
        const uint4 ca = *(const uint4*)(vb2 + eo);
        const uint4 cb = *(const uint4*)(vb2 + eo + 8);
        const f32x2 w2 = {w, w};
        acc[0] += w2 * bfpair(ca.x);
        acc[1] += w2 * bfpair(ca.y);
        acc[2] += w2 * bfpair(ca.z);
        acc[3] += w2 * bfpair(ca.w);
        acc[4] += w2 * bfpair(cb.x);
        acc[5] += w2 * bfpair(cb.y);
        acc[6] += w2 * bfpair(cb.z);
        acc[7] += w2 * bfpair(cb.w);
    };

    #pragma unroll
    for (int l = 0; l < NLEV; l++) {
        const int H = Hs[l], W = Ws[l];
        const unsigned int base2 = (unsigned int)(Ss[l] * HDIM + dl);
        const float fx = rxs[l] * (float)W - 0.5f;
        const float fy = rys[l] * (float)H - 0.5f;
        const float4 o0 = *(const float4*)&po[l * 8];
        const float4 o1 = *(const float4*)&po[l * 8 + 4];
        const float4 a4 = *(const float4*)&pa[l * 4];
        const float oxs[4] = {o0.x, o0.z, o1.x, o1.z};
        const float oys[4] = {o0.y, o0.w, o1.y, o1.w};
        const float avs[4] = {a4.x, a4.y, a4.z, a4.w};
        #pragma unroll
        for (int p = 0; p < NPTS; p++) {
            const float x = fx + oxs[p];
            const float y = fy + oys[p];
            const float x0f = floorf(x), y0f = floorf(y);
            const int x0 = (int)x0f, y0 = (int)y0f;
            const float wx1 = x - x0f, wy1 = y - y0f;
            const float wx0 = 1.0f - wx1, wy0 = 1.0f - wy1;
            // clamped (always-valid) coords
            const int xc0 = min(max(x0, 0), W - 1);
            const int xc1 = min(max(x0 + 1, 0), W - 1);
            const int yc0 = min(max(y0, 0), H - 1);
            const int yc1 = min(max(y0 + 1, 0), H - 1);
            // OOB corners contribute weight 0 (== reference zero-padding)
            const float a = avs[p];
            const float ay0 = ((unsigned int)y0 < (unsigned int)H) ? a * wy0 : 0.f;
            const float ay1 = ((unsigned int)(y0 + 1) < (unsigned int)H) ? a * wy1 : 0.f;
            const float mx0 = ((unsigned int)x0 < (unsigned int)W) ? wx0 : 0.f;
            const float mx1 = ((unsigned int)(x0 + 1) < (unsigned int)W) ? wx1 : 0.f;

            const unsigned int ro0 = base2 + (unsigned int)(yc0 * W) * HDIM;
            const unsigned int ro1 = base2 + (unsigned int)(yc1 * W) * HDIM;
            corner(ro0 + (unsigned int)xc0 * HDIM, ay0 * mx0);
            corner(ro0 + (unsigned int)xc1 * HDIM, ay0 * mx1);
            corner(ro1 + (unsigned int)xc0 * HDIM, ay1 * mx0);
            corner(ro1 + (unsigned int)xc1 * HDIM, ay1 * mx1);
        }
    }

    union { uint4 u; unsigned short s[8]; } t0, t1;
    #pragma unroll
    for (int i = 0; i < 4; i++) {
        t0.s[2 * i]     = f2bf(acc[i].x);
        t0.s[2 * i + 1] = f2bf(acc[i].y);
        t1.s[2 * i]     = f2bf(acc[4 + i].x);
        t1.s[2 * i + 1] = f2bf(acc[4 + i].y);
    }
    unsigned short* op = Ocat + (size_t)nq * 512 + it * 256 + h * HDIM + dl;
    *(uint4*)op = t0.u;
    *(uint4*)(op + 8) = t1.u;
}

// ---------------------------------------------------------------------------
extern "C" void kernel_launch(void* const* d_in, const int* in_sizes, int n_in,
                              void* d_out, int out_size, void* d_ws, size_t ws_size,
                              hipStream_t stream)
{
    const float* q0    = (const float*)d_in[0];
    const float* q1    = (const float*)d_in[1];
    const float* refp  = (const float*)d_in[2];
    const float* f0    = (const float*)d_in[3];
    const float* f1    = (const float*)d_in[4];
    const float* W_so  = (const float*)d_in[7];
    const float* b_so  = (const float*)d_in[8];
    const float* W_aw  = (const float*)d_in[9];
    const float* b_aw  = (const float*)d_in[10];
    const float* W_v   = (const float*)d_in[11];
    const float* b_v   = (const float*)d_in[12];
    const float* W_o   = (const float*)d_in[13];
    const float* b_o   = (const float*)d_in[14];
    const float* W_agg = (const float*)d_in[15];
    const float* b_agg = (const float*)d_in[16];
    float* out = (float*)d_out;

    float* ws = (float*)d_ws;
    float* QS0 = ws;                                        // NQ*384 fp32
    float* QS1 = QS0 + (size_t)NQ * LDQS;                   // NQ*384 fp32
    unsigned short* V0   = (unsigned short*)(QS1 + (size_t)NQ * LDQS);  // NQ*256 bf16
    unsigned short* V1   = V0 + (size_t)NQ * 256;
    unsigned short* Ocat = V1 + (size_t)NQ * 256;           // NQ*512 bf16
    unsigned short* Wvt    = Ocat + (size_t)NQ * 512;       // 65536
    unsigned short* Wsoawt = Wvt + 65536;                   // 98304
    unsigned short* Wfcat  = Wsoawt + 98304;                // 131072
    float* bsoaw = (float*)(Wfcat + 131072);                // 384
    float* bf    = bsoaw + 384;                             // 256

    const int MB = (NQ + 127) / 128;   // 306
    dim3 blk(256);

    prep_weights<<<640, blk, 0, stream>>>(W_v, W_so, W_aw, b_so, b_aw, Wvt, Wsoawt, bsoaw);
    fuse_weights<<<256, blk, 0, stream>>>(W_o, W_agg, b_o, b_agg, Wfcat, bf);

    // q-side: offsets + logits for both iters in one batched GEMM
    gemm_multi<<<dim3(3, MB, 2), blk, 0, stream>>>(
        q0, q1, Wsoawt, bsoaw, QS0, QS1, NQ, 256, 256, 384, LDQS, 0, 0);

    joint_softmax<<<(NQ * NHEADS + 255) / 256, blk, 0, stream>>>(QS0, QS1);

    // values for both iters, head-major scatter
    gemm_multi<<<dim3(2, MB, 2), blk, 0, stream>>>(
        f0, f1, Wvt, b_v, V0, V1, NQ, 256, 256, 256, 256, 0, 2);

    // merged sampler (both iters) -> Ocat; 2 it * 2 n * CHUNKS * 8 heads
    ms_sample<<<2 * 2 * CHUNKS * 8, blk, 0, stream>>>(V0, V1, QS0, QS1, refp, Ocat);

    // single K=512 tail GEMM -> out
    gemm_multi<<<dim3(2, MB, 1), blk, 0, stream>>>(
        Ocat, Ocat, Wfcat, bf, out, out, NQ, 512, 512, 256, 256, 1, 0);
}

// Round 2
// 620.845 us; speedup vs baseline: 1.1377x; 1.1377x over previous
//
#include <hip/hip_runtime.h>
#include <math.h>

#define NBATCH 2
#define LQ     19560
#define LEN    19560
#define NQ     (NBATCH * LQ)      // 39120
#define DMODEL 256
#define NHEADS 8
#define HDIM   32
#define NLEV   4
#define NPTS   4
#define LDQS   384                // QS row stride: [0..255]=offsets, [256..383]=logits/aw

typedef __bf16 bf16x8 __attribute__((ext_vector_type(8)));
typedef float  f32x4  __attribute__((ext_vector_type(4)));
typedef float  f32x2  __attribute__((ext_vector_type(2)));

__device__ inline float bf2f(unsigned short u) {
    return __uint_as_float(((unsigned int)u) << 16);
}
__device__ inline unsigned short f2bf(float f) {
    unsigned int u = __float_as_uint(f);
    u += 0x7FFFu + ((u >> 16) & 1u);     // RNE
    return (unsigned short)(u >> 16);
}
// two bf16 packed in a dword -> two exact f32 (lo = u<<16, hi = u & 0xFFFF0000)
__device__ inline f32x2 bfpair(unsigned int u) {
    f32x2 r;
    r.x = __uint_as_float(u << 16);
    r.y = __uint_as_float(u & 0xFFFF0000u);
    return r;
}

// ---------------------------------------------------------------------------
// Batched bf16 MFMA GEMM: C_z = A_z @ Bt^T (+bias), z = blockIdx.z
// A: fp32 (a_bf16=0, converted in staging) or bf16 (a_bf16=1), row stride lda.
// Bt: bf16 [N][K] row stride K. 128x128 tile, BK=64, 4 waves, 4x4 16x16x32 MFMA.
// mode 0: store fp32 at C[row*ldc+col]
// mode 2: store bf16 head-major scatter (n, h, pos, d)  [value tensor]
// ---------------------------------------------------------------------------
#define LDK 72

__global__ __launch_bounds__(256) void gemm_multi(
    const void* __restrict__ A0, const void* __restrict__ A1,
    const unsigned short* __restrict__ Bt, const float* __restrict__ bias,
    void* __restrict__ C0, void* __restrict__ C1,
    int M, int K, int lda, int N, int ldc, int a_bf16, int mode)
{
    __shared__ unsigned short As[128 * LDK];
    __shared__ unsigned short Bs[128 * LDK];

    const int z = blockIdx.z;
    const void* A = z ? A1 : A0;
    void* Cv = z ? C1 : C0;

    const int tid  = threadIdx.x;
    const int wave = tid >> 6, lane = tid & 63;
    const int wm = wave >> 1, wn = wave & 1;
    const int m0 = blockIdx.y * 128, n0 = blockIdx.x * 128;
    const int lr = lane & 15, quad = lane >> 4;

    const f32x4 zero = {0.f, 0.f, 0.f, 0.f};
    f32x4 acc[4][4];
    #pragma unroll
    for (int i = 0; i < 4; i++)
        #pragma unroll
        for (int j = 0; j < 4; j++) acc[i][j] = zero;

    for (int t = 0; t < K; t += 64) {
        #pragma unroll
        for (int i = 0; i < 4; i++) {
            int v = tid + i * 256;
            int r = v >> 3, c = v & 7;
            int row = m0 + r;
            uint4 d = make_uint4(0, 0, 0, 0);
            if (row < M) {
                if (a_bf16) {
                    d = *(const uint4*)&((const unsigned short*)A)[(size_t)row * lda + t + c * 8];
                } else {
                    const float* ap = &((const float*)A)[(size_t)row * lda + t + c * 8];
                    float4 x = *(const float4*)ap;
                    float4 y = *(const float4*)(ap + 4);
                    union { uint4 u; unsigned short s[8]; } tmp;
                    tmp.s[0] = f2bf(x.x); tmp.s[1] = f2bf(x.y);
                    tmp.s[2] = f2bf(x.z); tmp.s[3] = f2bf(x.w);
                    tmp.s[4] = f2bf(y.x); tmp.s[5] = f2bf(y.y);
                    tmp.s[6] = f2bf(y.z); tmp.s[7] = f2bf(y.w);
                    d = tmp.u;
                }
            }
            *(uint4*)&As[r * LDK + c * 8] = d;
        }
        #pragma unroll
        for (int i = 0; i < 4; i++) {
            int v = tid + i * 256;
            int r = v >> 3, c = v & 7;
            uint4 d = make_uint4(0, 0, 0, 0);
            if (n0 + r < N) d = *(const uint4*)&Bt[(size_t)(n0 + r) * K + t + c * 8];
            *(uint4*)&Bs[r * LDK + c * 8] = d;
        }
        __syncthreads();

        #pragma unroll
        for (int kk = 0; kk < 2; kk++) {
            bf16x8 af[4], bff[4];
            #pragma unroll
            for (int mi = 0; mi < 4; mi++)
                af[mi] = *(const bf16x8*)&As[(wm * 64 + mi * 16 + lr) * LDK + kk * 32 + quad * 8];
            #pragma unroll
            for (int ni = 0; ni < 4; ni++)
                bff[ni] = *(const bf16x8*)&Bs[(wn * 64 + ni * 16 + lr) * LDK + kk * 32 + quad * 8];
            #pragma unroll
            for (int mi = 0; mi < 4; mi++)
                #pragma unroll
                for (int ni = 0; ni < 4; ni++)
                    acc[mi][ni] = __builtin_amdgcn_mfma_f32_16x16x32_bf16(
                        af[mi], bff[ni], acc[mi][ni], 0, 0, 0);
        }
        __syncthreads();
    }

    float* Cf = (float*)Cv;
    unsigned short* Cb = (unsigned short*)Cv;
    #pragma unroll
    for (int mi = 0; mi < 4; mi++) {
        #pragma unroll
        for (int reg = 0; reg < 4; reg++) {
            int row = m0 + wm * 64 + mi * 16 + quad * 4 + reg;
            if (row >= M) continue;
            #pragma unroll
            for (int ni = 0; ni < 4; ni++) {
                int col = n0 + wn * 64 + ni * 16 + lr;
                float v = acc[mi][ni][reg];
                if (bias) v += bias[col];
                if (mode == 0) {
                    Cf[(size_t)row * ldc + col] = v;
                } else {
                    int n = row >= LQ ? 1 : 0;
                    int pos = row - n * LQ;
                    int h = col >> 5, d = col & 31;
                    Cb[((size_t)(n * NHEADS + h) * LEN + pos) * HDIM + d] = f2bf(v);
                }
            }
        }
    }
}

// ---------------------------------------------------------------------------
// Weight prep: Wvt[n][k]=bf16(Wv[k][n]); Wsoawt[n][k]: n<256 from W_so, else W_aw.
// bsoaw = [b_so | b_aw] fp32(384).
// ---------------------------------------------------------------------------
__global__ __launch_bounds__(256) void prep_weights(
    const float* __restrict__ Wv, const float* __restrict__ Wso,
    const float* __restrict__ Waw, const float* __restrict__ bso,
    const float* __restrict__ baw, unsigned short* __restrict__ Wvt,
    unsigned short* __restrict__ Wsoawt, float* __restrict__ bsoaw)
{
    int o = blockIdx.x * 256 + threadIdx.x;
    if (o < 65536) {
        int n = o >> 8, k = o & 255;
        Wvt[o] = f2bf(Wv[(size_t)k * 256 + n]);
    } else if (o < 65536 + 98304) {
        int p = o - 65536;
        int n = p >> 8, k = p & 255;
        float v = (n < 256) ? Wso[(size_t)k * 256 + n] : Waw[(size_t)k * 128 + (n - 256)];
        Wsoawt[p] = f2bf(v);
    }
    if (o < 384) bsoaw[o] = (o < 256) ? bso[o] : baw[o - 256];
}

// ---------------------------------------------------------------------------
// Fused tail weights, concatenated K=512: Wfcat[n][k] = bf16((Wo@Wagg0)[k][n]),
// Wfcat[n][256+k] = bf16((Wo@Wagg1)[k][n]); bf = b_o@(Wagg0+Wagg1)+b_agg.
// ---------------------------------------------------------------------------
__global__ __launch_bounds__(256) void fuse_weights(
    const float* __restrict__ Wo, const float* __restrict__ Wagg,
    const float* __restrict__ bo, const float* __restrict__ bagg,
    unsigned short* __restrict__ Wfcat, float* __restrict__ bf)
{
    int n = threadIdx.x;
    int k = blockIdx.x;
    float s0 = 0.f, s1 = 0.f;
    for (int j = 0; j < 256; j++) {
        float w = Wo[k * 256 + j];
        s0 += w * Wagg[j * 256 + n];
        s1 += w * Wagg[(256 + j) * 256 + n];
    }
    Wfcat[(size_t)n * 512 + k]       = f2bf(s0);
    Wfcat[(size_t)n * 512 + 256 + k] = f2bf(s1);
    if (k == 0) {
        float b = bagg[n];
        for (int j = 0; j < 256; j++)
            b += bo[j] * (Wagg[j * 256 + n] + Wagg[(256 + j) * 256 + n]);
        bf[n] = b;
    }
}

// ---------------------------------------------------------------------------
// Joint softmax over 32 logits per (n,q,h): QS cols [256..383], in-place
// ---------------------------------------------------------------------------
__global__ __launch_bounds__(256) void joint_softmax(float* __restrict__ QS0,
                                                     float* __restrict__ QS1)
{
    int r = blockIdx.x * 256 + threadIdx.x;
    if (r >= NQ * NHEADS) return;
    int nq = r >> 3, h = r & 7;
    float* p0 = QS0 + (size_t)nq * LDQS + 256 + h * 16;
    float* p1 = QS1 + (size_t)nq * LDQS + 256 + h * 16;
    float v[32];
    #pragma unroll
    for (int i = 0; i < 16; i++) { v[i] = p0[i]; v[16 + i] = p1[i]; }
    float m = v[0];
    #pragma unroll
    for (int i = 1; i < 32; i++) m = fmaxf(m, v[i]);
    float s = 0.f;
    #pragma unroll
    for (int i = 0; i < 32; i++) { v[i] = expf(v[i] - m); s += v[i]; }
    float inv = 1.0f / s;
    #pragma unroll
    for (int i = 0; i < 16; i++) { p0[i] = v[i] * inv; p1[i] = v[16 + i] * inv; }
}

// ---------------------------------------------------------------------------
// Merged deformable sampling (both iters), v3:
//  - v1 lane layout restored: 64 queries/block, 4 lanes/query, lane owns 8 dims
//    -> one global_load_dwordx4 per corner per lane; a wave's 64 lanes touch 16
//    distinct 64B value rows per instruction, each row consumed by exactly one
//    instruction (v2's 2-lane split doubled per-row line-touches; regressed).
//  - kept from v2: division-free coords (ref*W - 0.5 + off; /W*W cancels),
//    block-uniform slab base (it,n,h uniform -> SGPR base + 32-bit offsets),
//    branchless corners (clamp coords, zero OOB weights; unconditional issue),
//    packed f32x2 accumulate (v_pk_fma_f32).
//  - grid: b = (((it*2+n)*CHUNKS + chunk) << 3) | h; b&7==h keeps per-(n,h)
//    1.25MB value slab XCD-local; it in high bits = temporal phasing.
// ---------------------------------------------------------------------------
#define QCHUNK 64
#define CHUNKS ((LQ + QCHUNK - 1) / QCHUNK)   // 306

__global__ __launch_bounds__(256) void ms_sample(
    const unsigned short* __restrict__ V0, const unsigned short* __restrict__ V1,
    const float* __restrict__ QS0, const float* __restrict__ QS1,
    const float* __restrict__ refp, unsigned short* __restrict__ Ocat)
{
    const int b = blockIdx.x;
    const int h = b & 7;
    const int rest = b >> 3;               // (it*2+n)*CHUNKS + chunk
    const int chunk = rest % CHUNKS;
    const int inn   = rest / CHUNKS;       // it*2 + n
    const int n  = inn & 1;
    const int it = inn >> 1;

    const int tid = threadIdx.x;
    const int ql  = tid >> 2;              // 0..63
    const int dl  = (tid & 3) << 3;        // element offset 0,8,16,24
    const int q   = chunk * QCHUNK + ql;   // within batch
    if (q >= LQ) return;
    const int nq  = n * LQ + q;

    const unsigned short* __restrict__ val = it ? V1 : V0;
    const float* __restrict__ QS = it ? QS1 : QS0;
    // block-uniform slab base -> SGPR base, 32-bit unsigned element offsets
    const unsigned short* __restrict__ vb2 =
        val + (size_t)(n * NHEADS + h) * LEN * HDIM;

    const int Hs[4] = {92, 46, 23, 12};
    const int Ws[4] = {160, 80, 40, 20};
    const int Ss[4] = {0, 14720, 18400, 19320};

    const float* prow = QS + (size_t)nq * LDQS;
    const float* po = prow + (h << 5);            // this head's 32 offset floats
    const float* pa = prow + 256 + (h << 4);      // this head's 16 attn weights
    const float4 rp01 = *(const float4*)(refp + (size_t)nq * 8);
    const float4 rp23 = *(const float4*)(refp + (size_t)nq * 8 + 4);
    const float rxs[4] = {rp01.x, rp01.z, rp23.x, rp23.z};
    const float rys[4] = {rp01.y, rp01.w, rp23.y, rp23.w};

    f32x2 acc[4];
    #pragma unroll
    for (int i = 0; i < 4; i++) acc[i] = (f32x2){0.f, 0.f};

    auto corner = [&](unsigned int eo, float w) {
        const uint4 c = *(const uint4*)(vb2 + eo);
        const f32x2 w2 = {w, w};
        acc[0] += w2 * bfpair(c.x);
        acc[1] += w2 * bfpair(c.y);
        acc[2] += w2 * bfpair(c.z);
        acc[3] += w2 * bfpair(c.w);
    };

    #pragma unroll
    for (int l = 0; l < NLEV; l++) {
        const int H = Hs[l], W = Ws[l];
        const unsigned int base2 = (unsigned int)(Ss[l] * HDIM + dl);
        const float fx = rxs[l] * (float)W - 0.5f;
        const float fy = rys[l] * (float)H - 0.5f;
        const float4 o0 = *(const float4*)&po[l * 8];
        const float4 o1 = *(const float4*)&po[l * 8 + 4];
        const float4 a4 = *(const float4*)&pa[l * 4];
        const float oxs[4] = {o0.x, o0.z, o1.x, o1.z};
        const float oys[4] = {o0.y, o0.w, o1.y, o1.w};
        const float avs[4] = {a4.x, a4.y, a4.z, a4.w};
        #pragma unroll
        for (int p = 0; p < NPTS; p++) {
            const float x = fx + oxs[p];
            const float y = fy + oys[p];
            const float x0f = floorf(x), y0f = floorf(y);
            const int x0 = (int)x0f, y0 = (int)y0f;
            const float wx1 = x - x0f, wy1 = y - y0f;
            const float wx0 = 1.0f - wx1, wy0 = 1.0f - wy1;
            // clamped (always-valid) coords
            const int xc0 = min(max(x0, 0), W - 1);
            const int xc1 = min(max(x0 + 1, 0), W - 1);
            const int yc0 = min(max(y0, 0), H - 1);
            const int yc1 = min(max(y0 + 1, 0), H - 1);
            // OOB corners contribute weight 0 (== reference zero-padding)
            const float a = avs[p];
            const float ay0 = ((unsigned int)y0 < (unsigned int)H) ? a * wy0 : 0.f;
            const float ay1 = ((unsigned int)(y0 + 1) < (unsigned int)H) ? a * wy1 : 0.f;
            const float mx0 = ((unsigned int)x0 < (unsigned int)W) ? wx0 : 0.f;
            const float mx1 = ((unsigned int)(x0 + 1) < (unsigned int)W) ? wx1 : 0.f;

            const unsigned int ro0 = base2 + (unsigned int)(yc0 * W) * HDIM;
            const unsigned int ro1 = base2 + (unsigned int)(yc1 * W) * HDIM;
            corner(ro0 + (unsigned int)xc0 * HDIM, ay0 * mx0);
            corner(ro0 + (unsigned int)xc1 * HDIM, ay0 * mx1);
            corner(ro1 + (unsigned int)xc0 * HDIM, ay1 * mx0);
            corner(ro1 + (unsigned int)xc1 * HDIM, ay1 * mx1);
        }
    }

    union { uint4 u; unsigned short s[8]; } t;
    #pragma unroll
    for (int i = 0; i < 4; i++) {
        t.s[2 * i]     = f2bf(acc[i].x);
        t.s[2 * i + 1] = f2bf(acc[i].y);
    }
    *(uint4*)&Ocat[(size_t)nq * 512 + it * 256 + h * HDIM + dl] = t.u;
}

// ---------------------------------------------------------------------------
extern "C" void kernel_launch(void* const* d_in, const int* in_sizes, int n_in,
                              void* d_out, int out_size, void* d_ws, size_t ws_size,
                              hipStream_t stream)
{
    const float* q0    = (const float*)d_in[0];
    const float* q1    = (const float*)d_in[1];
    const float* refp  = (const float*)d_in[2];
    const float* f0    = (const float*)d_in[3];
    const float* f1    = (const float*)d_in[4];
    const float* W_so  = (const float*)d_in[7];
    const float* b_so  = (const float*)d_in[8];
    const float* W_aw  = (const float*)d_in[9];
    const float* b_aw  = (const float*)d_in[10];
    const float* W_v   = (const float*)d_in[11];
    const float* b_v   = (const float*)d_in[12];
    const float* W_o   = (const float*)d_in[13];
    const float* b_o   = (const float*)d_in[14];
    const float* W_agg = (const float*)d_in[15];
    const float* b_agg = (const float*)d_in[16];
    float* out = (float*)d_out;

    float* ws = (float*)d_ws;
    float* QS0 = ws;                                        // NQ*384 fp32
    float* QS1 = QS0 + (size_t)NQ * LDQS;                   // NQ*384 fp32
    unsigned short* V0   = (unsigned short*)(QS1 + (size_t)NQ * LDQS);  // NQ*256 bf16
    unsigned short* V1   = V0 + (size_t)NQ * 256;
    unsigned short* Ocat = V1 + (size_t)NQ * 256;           // NQ*512 bf16
    unsigned short* Wvt    = Ocat + (size_t)NQ * 512;       // 65536
    unsigned short* Wsoawt = Wvt + 65536;                   // 98304
    unsigned short* Wfcat  = Wsoawt + 98304;                // 131072
    float* bsoaw = (float*)(Wfcat + 131072);                // 384
    float* bf    = bsoaw + 384;                             // 256

    const int MB = (NQ + 127) / 128;   // 306
    dim3 blk(256);

    prep_weights<<<640, blk, 0, stream>>>(W_v, W_so, W_aw, b_so, b_aw, Wvt, Wsoawt, bsoaw);
    fuse_weights<<<256, blk, 0, stream>>>(W_o, W_agg, b_o, b_agg, Wfcat, bf);

    // q-side: offsets + logits for both iters in one batched GEMM
    gemm_multi<<<dim3(3, MB, 2), blk, 0, stream>>>(
        q0, q1, Wsoawt, bsoaw, QS0, QS1, NQ, 256, 256, 384, LDQS, 0, 0);

    joint_softmax<<<(NQ * NHEADS + 255) / 256, blk, 0, stream>>>(QS0, QS1);

    // values for both iters, head-major scatter
    gemm_multi<<<dim3(2, MB, 2), blk, 0, stream>>>(
        f0, f1, Wvt, b_v, V0, V1, NQ, 256, 256, 256, 256, 0, 2);

    // merged sampler (both iters) -> Ocat; 2 it * 2 n * CHUNKS * 8 heads
    ms_sample<<<2 * 2 * CHUNKS * 8, blk, 0, stream>>>(V0, V1, QS0, QS1, refp, Ocat);

    // single K=512 tail GEMM -> out
    gemm_multi<<<dim3(2, MB, 1), blk, 0, stream>>>(
        Ocat, Ocat, Wfcat, bf, out, out, NQ, 512, 512, 256, 256, 1, 0);
}

// Round 3
// 606.089 us; speedup vs baseline: 1.1654x; 1.0243x over previous
//
#include <hip/hip_runtime.h>
#include <math.h>

#define NBATCH 2
#define LQ     19560
#define LEN    19560
#define NQ     (NBATCH * LQ)      // 39120
#define DMODEL 256
#define NHEADS 8
#define HDIM   32
#define NLEV   4
#define NPTS   4
#define LDQS   384                // QS row stride: [0..255]=offsets, [256..383]=logits/aw

typedef __bf16 bf16x8 __attribute__((ext_vector_type(8)));
typedef float  f32x4  __attribute__((ext_vector_type(4)));
typedef float  f32x2  __attribute__((ext_vector_type(2)));

__device__ inline float bf2f(unsigned short u) {
    return __uint_as_float(((unsigned int)u) << 16);
}
__device__ inline unsigned short f2bf(float f) {
    unsigned int u = __float_as_uint(f);
    u += 0x7FFFu + ((u >> 16) & 1u);     // RNE
    return (unsigned short)(u >> 16);
}
// two bf16 packed in a dword -> two exact f32 (lo = u<<16, hi = u & 0xFFFF0000)
__device__ inline f32x2 bfpair(unsigned int u) {
    f32x2 r;
    r.x = __uint_as_float(u << 16);
    r.y = __uint_as_float(u & 0xFFFF0000u);
    return r;
}

// ---------------------------------------------------------------------------
// fp32 -> bf16 streaming convert for the four big A matrices.
// grid (4890, 4): y selects tensor; x*256+tid -> one 8-float chunk (exact fit).
// ---------------------------------------------------------------------------
__global__ __launch_bounds__(256) void convert_bf16(
    const float* __restrict__ q0, const float* __restrict__ q1,
    const float* __restrict__ f0, const float* __restrict__ f1,
    unsigned short* __restrict__ Qb0, unsigned short* __restrict__ Qb1,
    unsigned short* __restrict__ Fb0, unsigned short* __restrict__ Fb1)
{
    const int tsel = blockIdx.y;
    const float* s = (tsel & 2) ? ((tsel & 1) ? f1 : f0) : ((tsel & 1) ? q1 : q0);
    unsigned short* d = (tsel & 2) ? ((tsel & 1) ? Fb1 : Fb0) : ((tsel & 1) ? Qb1 : Qb0);
    size_t i = ((size_t)blockIdx.x * 256 + threadIdx.x) * 8;
    float4 a = *(const float4*)(s + i);
    float4 b = *(const float4*)(s + i + 4);
    union { uint4 u; unsigned short h[8]; } t;
    t.h[0] = f2bf(a.x); t.h[1] = f2bf(a.y); t.h[2] = f2bf(a.z); t.h[3] = f2bf(a.w);
    t.h[4] = f2bf(b.x); t.h[5] = f2bf(b.y); t.h[6] = f2bf(b.z); t.h[7] = f2bf(b.w);
    *(uint4*)(d + i) = t.u;
}

// ---------------------------------------------------------------------------
// Batched bf16 MFMA GEMM: C_z = A_z @ Bt^T (+bias), z = blockIdx.z
// A: bf16 [M][lda]; Bt: bf16 [N][K]. 128x128 tile, BK=64, 4 waves, 4x4 MFMA.
// Staging: global_load_lds width=16 DMA for A and B, LDS linear [128][128B],
// XOR chunk swizzle (source-side pre-swizzle + swizzled ds_read) to break the
// 128B-row-stride bank clustering on ds_read_b128.
// M edge: per-lane SOURCE row clamp (epilogue guards the store).
// mode 0: store fp32 at C[row*ldc+col]
// mode 2: store bf16 head-major scatter (n, h, pos, d)  [value tensor]
// ---------------------------------------------------------------------------
__global__ __launch_bounds__(256) void gemm_multi(
    const unsigned short* __restrict__ A0, const unsigned short* __restrict__ A1,
    const unsigned short* __restrict__ Bt, const float* __restrict__ bias,
    void* __restrict__ C0, void* __restrict__ C1,
    int M, int K, int lda, int N, int ldc, int mode)
{
    __shared__ __align__(16) unsigned short As[128 * 64];
    __shared__ __align__(16) unsigned short Bs[128 * 64];

    const int z = blockIdx.z;
    const unsigned short* A = z ? A1 : A0;
    void* Cv = z ? C1 : C0;

    const int tid  = threadIdx.x;
    const int w    = tid >> 6, lane = tid & 63;
    const int wm = w >> 1, wn = w & 1;
    const int m0 = blockIdx.y * 128, n0 = blockIdx.x * 128;
    const int lr = lane & 15, quad = lane >> 4;

    // staging geometry: inst j covers physical rows R0=(w*4+j)*8 .. +7.
    // lane -> row-in-group sr = lane>>3, physical chunk scc = lane&7,
    // logical (source) chunk = scc ^ sr  (both-sides-consistent XOR swizzle).
    const int sr  = lane >> 3;
    const int scl = (lane & 7) ^ sr;
    const int colb = scl * 8;              // element offset within the K-chunk
    size_t arow[4], brow[4];
    #pragma unroll
    for (int j = 0; j < 4; j++) {
        int r = (w * 4 + j) * 8 + sr;
        int ra = m0 + r; if (ra > M - 1) ra = M - 1;   // clamp (source is per-lane)
        arow[j] = (size_t)ra * lda;
        brow[j] = (size_t)(n0 + r) * K;
    }

    const f32x4 zero = {0.f, 0.f, 0.f, 0.f};
    f32x4 acc[4][4];
    #pragma unroll
    for (int i = 0; i < 4; i++)
        #pragma unroll
        for (int j = 0; j < 4; j++) acc[i][j] = zero;

    for (int t = 0; t < K; t += 64) {
        #pragma unroll
        for (int j = 0; j < 4; j++) {
            int lofs = __builtin_amdgcn_readfirstlane((w * 4 + j) * 1024);
            __builtin_amdgcn_global_load_lds(
                (const __attribute__((address_space(1))) void*)(A + arow[j] + t + colb),
                (__attribute__((address_space(3))) void*)((char*)As + lofs), 16, 0, 0);
            __builtin_amdgcn_global_load_lds(
                (const __attribute__((address_space(1))) void*)(Bt + brow[j] + t + colb),
                (__attribute__((address_space(3))) void*)((char*)Bs + lofs), 16, 0, 0);
        }
        __syncthreads();   // compiler drains vmcnt before s_barrier

        #pragma unroll
        for (int kk = 0; kk < 2; kk++) {
            bf16x8 af[4], bff[4];
            #pragma unroll
            for (int mi = 0; mi < 4; mi++) {
                int R = wm * 64 + mi * 16 + lr;
                int pc = ((kk * 4 + quad) ^ (lr & 7)) * 16;
                af[mi] = *(const bf16x8*)((const char*)As + R * 128 + pc);
            }
            #pragma unroll
            for (int ni = 0; ni < 4; ni++) {
                int R = wn * 64 + ni * 16 + lr;
                int pc = ((kk * 4 + quad) ^ (lr & 7)) * 16;
                bff[ni] = *(const bf16x8*)((const char*)Bs + R * 128 + pc);
            }
            #pragma unroll
            for (int mi = 0; mi < 4; mi++)
                #pragma unroll
                for (int ni = 0; ni < 4; ni++)
                    acc[mi][ni] = __builtin_amdgcn_mfma_f32_16x16x32_bf16(
                        af[mi], bff[ni], acc[mi][ni], 0, 0, 0);
        }
        __syncthreads();
    }

    float* Cf = (float*)Cv;
    unsigned short* Cb = (unsigned short*)Cv;
    #pragma unroll
    for (int mi = 0; mi < 4; mi++) {
        #pragma unroll
        for (int reg = 0; reg < 4; reg++) {
            int row = m0 + wm * 64 + mi * 16 + quad * 4 + reg;
            if (row >= M) continue;
            #pragma unroll
            for (int ni = 0; ni < 4; ni++) {
                int col = n0 + wn * 64 + ni * 16 + lr;
                float v = acc[mi][ni][reg];
                if (bias) v += bias[col];
                if (mode == 0) {
                    Cf[(size_t)row * ldc + col] = v;
                } else {
                    int n = row >= LQ ? 1 : 0;
                    int pos = row - n * LQ;
                    int h = col >> 5, d = col & 31;
                    Cb[((size_t)(n * NHEADS + h) * LEN + pos) * HDIM + d] = f2bf(v);
                }
            }
        }
    }
}

// ---------------------------------------------------------------------------
// Weight prep: Wvt[n][k]=bf16(Wv[k][n]); Wsoawt[n][k]: n<256 from W_so, else W_aw.
// bsoaw = [b_so | b_aw] fp32(384).
// ---------------------------------------------------------------------------
__global__ __launch_bounds__(256) void prep_weights(
    const float* __restrict__ Wv, const float* __restrict__ Wso,
    const float* __restrict__ Waw, const float* __restrict__ bso,
    const float* __restrict__ baw, unsigned short* __restrict__ Wvt,
    unsigned short* __restrict__ Wsoawt, float* __restrict__ bsoaw)
{
    int o = blockIdx.x * 256 + threadIdx.x;
    if (o < 65536) {
        int n = o >> 8, k = o & 255;
        Wvt[o] = f2bf(Wv[(size_t)k * 256 + n]);
    } else if (o < 65536 + 98304) {
        int p = o - 65536;
        int n = p >> 8, k = p & 255;
        float v = (n < 256) ? Wso[(size_t)k * 256 + n] : Waw[(size_t)k * 128 + (n - 256)];
        Wsoawt[p] = f2bf(v);
    }
    if (o < 384) bsoaw[o] = (o < 256) ? bso[o] : baw[o - 256];
}

// ---------------------------------------------------------------------------
// Fused tail weights, concatenated K=512: Wfcat[n][k] = bf16((Wo@Wagg0)[k][n]),
// Wfcat[n][256+k] = bf16((Wo@Wagg1)[k][n]); bf = b_o@(Wagg0+Wagg1)+b_agg.
// ---------------------------------------------------------------------------
__global__ __launch_bounds__(256) void fuse_weights(
    const float* __restrict__ Wo, const float* __restrict__ Wagg,
    const float* __restrict__ bo, const float* __restrict__ bagg,
    unsigned short* __restrict__ Wfcat, float* __restrict__ bf)
{
    int n = threadIdx.x;
    int k = blockIdx.x;
    float s0 = 0.f, s1 = 0.f;
    for (int j = 0; j < 256; j++) {
        float w = Wo[k * 256 + j];
        s0 += w * Wagg[j * 256 + n];
        s1 += w * Wagg[(256 + j) * 256 + n];
    }
    Wfcat[(size_t)n * 512 + k]       = f2bf(s0);
    Wfcat[(size_t)n * 512 + 256 + k] = f2bf(s1);
    if (k == 0) {
        float b = bagg[n];
        for (int j = 0; j < 256; j++)
            b += bo[j] * (Wagg[j * 256 + n] + Wagg[(256 + j) * 256 + n]);
        bf[n] = b;
    }
}

// ---------------------------------------------------------------------------
// Joint softmax over 32 logits per (n,q,h): QS cols [256..383], in-place
// ---------------------------------------------------------------------------
__global__ __launch_bounds__(256) void joint_softmax(float* __restrict__ QS0,
                                                     float* __restrict__ QS1)
{
    int r = blockIdx.x * 256 + threadIdx.x;
    if (r >= NQ * NHEADS) return;
    int nq = r >> 3, h = r & 7;
    float* p0 = QS0 + (size_t)nq * LDQS + 256 + h * 16;
    float* p1 = QS1 + (size_t)nq * LDQS + 256 + h * 16;
    float v[32];
    #pragma unroll
    for (int i = 0; i < 16; i++) { v[i] = p0[i]; v[16 + i] = p1[i]; }
    float m = v[0];
    #pragma unroll
    for (int i = 1; i < 32; i++) m = fmaxf(m, v[i]);
    float s = 0.f;
    #pragma unroll
    for (int i = 0; i < 32; i++) { v[i] = expf(v[i] - m); s += v[i]; }
    float inv = 1.0f / s;
    #pragma unroll
    for (int i = 0; i < 16; i++) { p0[i] = v[i] * inv; p1[i] = v[16 + i] * inv; }
}

// ---------------------------------------------------------------------------
// Merged deformable sampling (both iters), v3 (unchanged from round 2):
//  - 64 queries/block, 4 lanes/query, lane owns 8 dims; one dwordx4 per corner
//  - division-free coords, block-uniform slab base, branchless clamped-weight
//    corners, packed f32x2 accumulate.
//  - grid: b = (((it*2+n)*CHUNKS + chunk) << 3) | h; b&7==h -> XCD affinity.
// ---------------------------------------------------------------------------
#define QCHUNK 64
#define CHUNKS ((LQ + QCHUNK - 1) / QCHUNK)   // 306

__global__ __launch_bounds__(256) void ms_sample(
    const unsigned short* __restrict__ V0, const unsigned short* __restrict__ V1,
    const float* __restrict__ QS0, const float* __restrict__ QS1,
    const float* __restrict__ refp, unsigned short* __restrict__ Ocat)
{
    const int b = blockIdx.x;
    const int h = b & 7;
    const int rest = b >> 3;               // (it*2+n)*CHUNKS + chunk
    const int chunk = rest % CHUNKS;
    const int inn   = rest / CHUNKS;       // it*2 + n
    const int n  = inn & 1;
    const int it = inn >> 1;

    const int tid = threadIdx.x;
    const int ql  = tid >> 2;              // 0..63
    const int dl  = (tid & 3) << 3;        // element offset 0,8,16,24
    const int q   = chunk * QCHUNK + ql;   // within batch
    if (q >= LQ) return;
    const int nq  = n * LQ + q;

    const unsigned short* __restrict__ val = it ? V1 : V0;
    const float* __restrict__ QS = it ? QS1 : QS0;
    const unsigned short* __restrict__ vb2 =
        val + (size_t)(n * NHEADS + h) * LEN * HDIM;

    const int Hs[4] = {92, 46, 23, 12};
    const int Ws[4] = {160, 80, 40, 20};
    const int Ss[4] = {0, 14720, 18400, 19320};

    const float* prow = QS + (size_t)nq * LDQS;
    const float* po = prow + (h << 5);            // this head's 32 offset floats
    const float* pa = prow + 256 + (h << 4);      // this head's 16 attn weights
    const float4 rp01 = *(const float4*)(refp + (size_t)nq * 8);
    const float4 rp23 = *(const float4*)(refp + (size_t)nq * 8 + 4);
    const float rxs[4] = {rp01.x, rp01.z, rp23.x, rp23.z};
    const float rys[4] = {rp01.y, rp01.w, rp23.y, rp23.w};

    f32x2 acc[4];
    #pragma unroll
    for (int i = 0; i < 4; i++) acc[i] = (f32x2){0.f, 0.f};

    auto corner = [&](unsigned int eo, float w) {
        const uint4 c = *(const uint4*)(vb2 + eo);
        const f32x2 w2 = {w, w};
        acc[0] += w2 * bfpair(c.x);
        acc[1] += w2 * bfpair(c.y);
        acc[2] += w2 * bfpair(c.z);
        acc[3] += w2 * bfpair(c.w);
    };

    #pragma unroll
    for (int l = 0; l < NLEV; l++) {
        const int H = Hs[l], W = Ws[l];
        const unsigned int base2 = (unsigned int)(Ss[l] * HDIM + dl);
        const float fx = rxs[l] * (float)W - 0.5f;
        const float fy = rys[l] * (float)H - 0.5f;
        const float4 o0 = *(const float4*)&po[l * 8];
        const float4 o1 = *(const float4*)&po[l * 8 + 4];
        const float4 a4 = *(const float4*)&pa[l * 4];
        const float oxs[4] = {o0.x, o0.z, o1.x, o1.z};
        const float oys[4] = {o0.y, o0.w, o1.y, o1.w};
        const float avs[4] = {a4.x, a4.y, a4.z, a4.w};
        #pragma unroll
        for (int p = 0; p < NPTS; p++) {
            const float x = fx + oxs[p];
            const float y = fy + oys[p];
            const float x0f = floorf(x), y0f = floorf(y);
            const int x0 = (int)x0f, y0 = (int)y0f;
            const float wx1 = x - x0f, wy1 = y - y0f;
            const float wx0 = 1.0f - wx1, wy0 = 1.0f - wy1;
            const int xc0 = min(max(x0, 0), W - 1);
            const int xc1 = min(max(x0 + 1, 0), W - 1);
            const int yc0 = min(max(y0, 0), H - 1);
            const int yc1 = min(max(y0 + 1, 0), H - 1);
            const float a = avs[p];
            const float ay0 = ((unsigned int)y0 < (unsigned int)H) ? a * wy0 : 0.f;
            const float ay1 = ((unsigned int)(y0 + 1) < (unsigned int)H) ? a * wy1 : 0.f;
            const float mx0 = ((unsigned int)x0 < (unsigned int)W) ? wx0 : 0.f;
            const float mx1 = ((unsigned int)(x0 + 1) < (unsigned int)W) ? wx1 : 0.f;

            const unsigned int ro0 = base2 + (unsigned int)(yc0 * W) * HDIM;
            const unsigned int ro1 = base2 + (unsigned int)(yc1 * W) * HDIM;
            corner(ro0 + (unsigned int)xc0 * HDIM, ay0 * mx0);
            corner(ro0 + (unsigned int)xc1 * HDIM, ay0 * mx1);
            corner(ro1 + (unsigned int)xc0 * HDIM, ay1 * mx0);
            corner(ro1 + (unsigned int)xc1 * HDIM, ay1 * mx1);
        }
    }

    union { uint4 u; unsigned short s[8]; } t;
    #pragma unroll
    for (int i = 0; i < 4; i++) {
        t.s[2 * i]     = f2bf(acc[i].x);
        t.s[2 * i + 1] = f2bf(acc[i].y);
    }
    *(uint4*)&Ocat[(size_t)nq * 512 + it * 256 + h * HDIM + dl] = t.u;
}

// ---------------------------------------------------------------------------
extern "C" void kernel_launch(void* const* d_in, const int* in_sizes, int n_in,
                              void* d_out, int out_size, void* d_ws, size_t ws_size,
                              hipStream_t stream)
{
    const float* q0    = (const float*)d_in[0];
    const float* q1    = (const float*)d_in[1];
    const float* refp  = (const float*)d_in[2];
    const float* f0    = (const float*)d_in[3];
    const float* f1    = (const float*)d_in[4];
    const float* W_so  = (const float*)d_in[7];
    const float* b_so  = (const float*)d_in[8];
    const float* W_aw  = (const float*)d_in[9];
    const float* b_aw  = (const float*)d_in[10];
    const float* W_v   = (const float*)d_in[11];
    const float* b_v   = (const float*)d_in[12];
    const float* W_o   = (const float*)d_in[13];
    const float* b_o   = (const float*)d_in[14];
    const float* W_agg = (const float*)d_in[15];
    const float* b_agg = (const float*)d_in[16];
    float* out = (float*)d_out;

    float* ws = (float*)d_ws;
    float* QS0 = ws;                                        // NQ*384 fp32
    float* QS1 = QS0 + (size_t)NQ * LDQS;                   // NQ*384 fp32
    unsigned short* V0   = (unsigned short*)(QS1 + (size_t)NQ * LDQS);  // NQ*256 bf16
    unsigned short* V1   = V0 + (size_t)NQ * 256;
    unsigned short* Ocat = V1 + (size_t)NQ * 256;           // NQ*512 bf16
    unsigned short* Wvt    = Ocat + (size_t)NQ * 512;       // 65536
    unsigned short* Wsoawt = Wvt + 65536;                   // 98304
    unsigned short* Wfcat  = Wsoawt + 98304;                // 131072
    float* bsoaw = (float*)(Wfcat + 131072);                // 384
    float* bf    = bsoaw + 384;                             // 256

    // bf16 A copies, zero extra workspace (lifetime-audited aliases):
    //  Qb0/Qb1 alias V0/V1   (q-GEMM reads them BEFORE value-GEMM writes V)
    //  Fb0/Fb1 alias Ocat    (value-GEMM reads them BEFORE ms_sample writes Ocat)
    unsigned short* Qb0 = V0;
    unsigned short* Qb1 = V1;
    unsigned short* Fb0 = Ocat;
    unsigned short* Fb1 = Ocat + (size_t)NQ * 256;

    const int MB = (NQ + 127) / 128;   // 306
    dim3 blk(256);

    convert_bf16<<<dim3(4890, 4), blk, 0, stream>>>(q0, q1, f0, f1, Qb0, Qb1, Fb0, Fb1);
    prep_weights<<<640, blk, 0, stream>>>(W_v, W_so, W_aw, b_so, b_aw, Wvt, Wsoawt, bsoaw);
    fuse_weights<<<256, blk, 0, stream>>>(W_o, W_agg, b_o, b_agg, Wfcat, bf);

    // q-side: offsets + logits for both iters (A = bf16 copies in V region)
    gemm_multi<<<dim3(3, MB, 2), blk, 0, stream>>>(
        Qb0, Qb1, Wsoawt, bsoaw, QS0, QS1, NQ, 256, 256, 384, LDQS, 0);

    joint_softmax<<<(NQ * NHEADS + 255) / 256, blk, 0, stream>>>(QS0, QS1);

    // values for both iters (A = bf16 copies in Ocat region), head-major scatter
    gemm_multi<<<dim3(2, MB, 2), blk, 0, stream>>>(
        Fb0, Fb1, Wvt, b_v, V0, V1, NQ, 256, 256, 256, 256, 2);

    // merged sampler (both iters) -> Ocat (overwrites Fb after value-GEMM)
    ms_sample<<<2 * 2 * CHUNKS * 8, blk, 0, stream>>>(V0, V1, QS0, QS1, refp, Ocat);

    // single K=512 tail GEMM -> out
    gemm_multi<<<dim3(2, MB, 1), blk, 0, stream>>>(
        Ocat, Ocat, Wfcat, bf, out, out, NQ, 512, 512, 256, 256, 0);
}

// Round 4
// 542.145 us; speedup vs baseline: 1.3028x; 1.1179x over previous
//
#include <hip/hip_runtime.h>
#include <math.h>

#define NBATCH 2
#define LQ     19560
#define LEN    19560
#define NQ     (NBATCH * LQ)      // 39120
#define DMODEL 256
#define NHEADS 8
#define HDIM   32
#define NLEV   4
#define NPTS   4
#define LDQS   384                // QS row stride: [0..255]=offsets, [256..383]=logits/aw

typedef __bf16 bf16x8 __attribute__((ext_vector_type(8)));
typedef float  f32x4  __attribute__((ext_vector_type(4)));
typedef float  f32x2  __attribute__((ext_vector_type(2)));

__device__ inline float bf2f(unsigned short u) {
    return __uint_as_float(((unsigned int)u) << 16);
}
__device__ inline unsigned short f2bf(float f) {
    unsigned int u = __float_as_uint(f);
    u += 0x7FFFu + ((u >> 16) & 1u);     // RNE
    return (unsigned short)(u >> 16);
}
// two bf16 packed in a dword -> two exact f32 (lo = u<<16, hi = u & 0xFFFF0000)
__device__ inline f32x2 bfpair(unsigned int u) {
    f32x2 r;
    r.x = __uint_as_float(u << 16);
    r.y = __uint_as_float(u & 0xFFFF0000u);
    return r;
}

// ---------------------------------------------------------------------------
// Merged preprocessing (one dispatch, disjoint outputs):
//   b in [0,19560):        fp32->bf16 convert of q0/q1/f0/f1 (tsel=b/4890)
//   b in [19560,20200):    weight transpose/pack (Wvt, Wsoawt, bsoaw)
//   b in [20200,20456):    fused tail weights Wfcat = (Wo@Wagg)^T bf16, bf
// ---------------------------------------------------------------------------
__global__ __launch_bounds__(256) void prep_all(
    const float* __restrict__ q0, const float* __restrict__ q1,
    const float* __restrict__ f0, const float* __restrict__ f1,
    const float* __restrict__ Wv, const float* __restrict__ Wso,
    const float* __restrict__ Waw, const float* __restrict__ bso,
    const float* __restrict__ baw,
    const float* __restrict__ Wo, const float* __restrict__ Wagg,
    const float* __restrict__ bo, const float* __restrict__ bagg,
    unsigned short* __restrict__ Qb0, unsigned short* __restrict__ Qb1,
    unsigned short* __restrict__ Fb0, unsigned short* __restrict__ Fb1,
    unsigned short* __restrict__ Wvt, unsigned short* __restrict__ Wsoawt,
    float* __restrict__ bsoaw,
    unsigned short* __restrict__ Wfcat, float* __restrict__ bfused)
{
    const int b = blockIdx.x;
    if (b < 19560) {
        const int tsel = b / 4890;
        const int x = b - tsel * 4890;
        const float* s = (tsel & 2) ? ((tsel & 1) ? f1 : f0) : ((tsel & 1) ? q1 : q0);
        unsigned short* d = (tsel & 2) ? ((tsel & 1) ? Fb1 : Fb0) : ((tsel & 1) ? Qb1 : Qb0);
        size_t i = ((size_t)x * 256 + threadIdx.x) * 8;
        float4 a = *(const float4*)(s + i);
        float4 c = *(const float4*)(s + i + 4);
        union { uint4 u; unsigned short h[8]; } t;
        t.h[0] = f2bf(a.x); t.h[1] = f2bf(a.y); t.h[2] = f2bf(a.z); t.h[3] = f2bf(a.w);
        t.h[4] = f2bf(c.x); t.h[5] = f2bf(c.y); t.h[6] = f2bf(c.z); t.h[7] = f2bf(c.w);
        *(uint4*)(d + i) = t.u;
    } else if (b < 19560 + 640) {
        int o = (b - 19560) * 256 + threadIdx.x;
        if (o < 65536) {
            int n = o >> 8, k = o & 255;
            Wvt[o] = f2bf(Wv[(size_t)k * 256 + n]);
        } else {
            int p = o - 65536;
            int n = p >> 8, k = p & 255;
            float v = (n < 256) ? Wso[(size_t)k * 256 + n] : Waw[(size_t)k * 128 + (n - 256)];
            Wsoawt[p] = f2bf(v);
        }
        if (o < 384) bsoaw[o] = (o < 256) ? bso[o] : baw[o - 256];
    } else {
        int k = b - 20200;
        int n = threadIdx.x;
        float s0 = 0.f, s1 = 0.f;
        for (int j = 0; j < 256; j++) {
            float w = Wo[k * 256 + j];
            s0 += w * Wagg[j * 256 + n];
            s1 += w * Wagg[(256 + j) * 256 + n];
        }
        Wfcat[(size_t)n * 512 + k]       = f2bf(s0);
        Wfcat[(size_t)n * 512 + 256 + k] = f2bf(s1);
        if (k == 0) {
            float bb = bagg[n];
            for (int j = 0; j < 256; j++)
                bb += bo[j] * (Wagg[j * 256 + n] + Wagg[(256 + j) * 256 + n]);
            bfused[n] = bb;
        }
    }
}

// ---------------------------------------------------------------------------
// Batched bf16 MFMA GEMM: C_z = A_z @ Bt^T (+bias), z = blockIdx.z
// A: bf16 [M][lda]; Bt: bf16 [N][K]. 128x128 tile, BK=64, 4 waves, 4x4 MFMA.
// Staging: global_load_lds width=16 DMA, LDS linear [128][128B], XOR chunk
// swizzle (source-side pre-swizzle + swizzled ds_read).
// mode 0: store fp32 at C[row*ldc+col]
// mode 2: store bf16 head-major scatter (n, h, pos, d)  [value tensor]
// ---------------------------------------------------------------------------
__global__ __launch_bounds__(256) void gemm_multi(
    const unsigned short* __restrict__ A0, const unsigned short* __restrict__ A1,
    const unsigned short* __restrict__ Bt, const float* __restrict__ bias,
    void* __restrict__ C0, void* __restrict__ C1,
    int M, int K, int lda, int N, int ldc, int mode)
{
    __shared__ __align__(16) unsigned short As[128 * 64];
    __shared__ __align__(16) unsigned short Bs[128 * 64];

    const int z = blockIdx.z;
    const unsigned short* A = z ? A1 : A0;
    void* Cv = z ? C1 : C0;

    const int tid  = threadIdx.x;
    const int w    = tid >> 6, lane = tid & 63;
    const int wm = w >> 1, wn = w & 1;
    const int m0 = blockIdx.y * 128, n0 = blockIdx.x * 128;
    const int lr = lane & 15, quad = lane >> 4;

    const int sr  = lane >> 3;
    const int scl = (lane & 7) ^ sr;
    const int colb = scl * 8;
    size_t arow[4], brow[4];
    #pragma unroll
    for (int j = 0; j < 4; j++) {
        int r = (w * 4 + j) * 8 + sr;
        int ra = m0 + r; if (ra > M - 1) ra = M - 1;
        arow[j] = (size_t)ra * lda;
        brow[j] = (size_t)(n0 + r) * K;
    }

    const f32x4 zero = {0.f, 0.f, 0.f, 0.f};
    f32x4 acc[4][4];
    #pragma unroll
    for (int i = 0; i < 4; i++)
        #pragma unroll
        for (int j = 0; j < 4; j++) acc[i][j] = zero;

    for (int t = 0; t < K; t += 64) {
        #pragma unroll
        for (int j = 0; j < 4; j++) {
            int lofs = __builtin_amdgcn_readfirstlane((w * 4 + j) * 1024);
            __builtin_amdgcn_global_load_lds(
                (const __attribute__((address_space(1))) void*)(A + arow[j] + t + colb),
                (__attribute__((address_space(3))) void*)((char*)As + lofs), 16, 0, 0);
            __builtin_amdgcn_global_load_lds(
                (const __attribute__((address_space(1))) void*)(Bt + brow[j] + t + colb),
                (__attribute__((address_space(3))) void*)((char*)Bs + lofs), 16, 0, 0);
        }
        __syncthreads();

        #pragma unroll
        for (int kk = 0; kk < 2; kk++) {
            bf16x8 af[4], bff[4];
            #pragma unroll
            for (int mi = 0; mi < 4; mi++) {
                int R = wm * 64 + mi * 16 + lr;
                int pc = ((kk * 4 + quad) ^ (lr & 7)) * 16;
                af[mi] = *(const bf16x8*)((const char*)As + R * 128 + pc);
            }
            #pragma unroll
            for (int ni = 0; ni < 4; ni++) {
                int R = wn * 64 + ni * 16 + lr;
                int pc = ((kk * 4 + quad) ^ (lr & 7)) * 16;
                bff[ni] = *(const bf16x8*)((const char*)Bs + R * 128 + pc);
            }
            #pragma unroll
            for (int mi = 0; mi < 4; mi++)
                #pragma unroll
                for (int ni = 0; ni < 4; ni++)
                    acc[mi][ni] = __builtin_amdgcn_mfma_f32_16x16x32_bf16(
                        af[mi], bff[ni], acc[mi][ni], 0, 0, 0);
        }
        __syncthreads();
    }

    float* Cf = (float*)Cv;
    unsigned short* Cb = (unsigned short*)Cv;
    #pragma unroll
    for (int mi = 0; mi < 4; mi++) {
        #pragma unroll
        for (int reg = 0; reg < 4; reg++) {
            int row = m0 + wm * 64 + mi * 16 + quad * 4 + reg;
            if (row >= M) continue;
            #pragma unroll
            for (int ni = 0; ni < 4; ni++) {
                int col = n0 + wn * 64 + ni * 16 + lr;
                float v = acc[mi][ni][reg];
                if (bias) v += bias[col];
                if (mode == 0) {
                    Cf[(size_t)row * ldc + col] = v;
                } else {
                    int n = row >= LQ ? 1 : 0;
                    int pos = row - n * LQ;
                    int h = col >> 5, d = col & 31;
                    Cb[((size_t)(n * NHEADS + h) * LEN + pos) * HDIM + d] = f2bf(v);
                }
            }
        }
    }
}

// ---------------------------------------------------------------------------
// Joint softmax over 32 logits per (n,q,h): QS cols [256..383], in-place
// ---------------------------------------------------------------------------
__global__ __launch_bounds__(256) void joint_softmax(float* __restrict__ QS0,
                                                     float* __restrict__ QS1)
{
    int r = blockIdx.x * 256 + threadIdx.x;
    if (r >= NQ * NHEADS) return;
    int nq = r >> 3, h = r & 7;
    float* p0 = QS0 + (size_t)nq * LDQS + 256 + h * 16;
    float* p1 = QS1 + (size_t)nq * LDQS + 256 + h * 16;
    float v[32];
    #pragma unroll
    for (int i = 0; i < 16; i++) { v[i] = p0[i]; v[16 + i] = p1[i]; }
    float m = v[0];
    #pragma unroll
    for (int i = 1; i < 32; i++) m = fmaxf(m, v[i]);
    float s = 0.f;
    #pragma unroll
    for (int i = 0; i < 32; i++) { v[i] = expf(v[i] - m); s += v[i]; }
    float inv = 1.0f / s;
    #pragma unroll
    for (int i = 0; i < 16; i++) { p0[i] = v[i] * inv; p1[i] = v[16 + i] * inv; }
}

// ---------------------------------------------------------------------------
// Merged deformable sampling (both iters), v4: two-phase LDS coord staging.
//  Phase 1: lane lj (=tid&3) of each query group owns LEVEL lj: computes that
//    level's 4 points (coords, clamps, 4 corner weights + u16 corner row-idx,
//    slab-level included: max 19558 < 65536) and stages them in LDS.
//    -> 4x dereplication of the coord/weight math AND of the QS loads.
//  Phase 2: identical gather layout to v3 (4 lanes/query, lane owns 8 dims,
//    one dwordx4 per corner) but reads {idx,wt} from LDS instead of
//    recomputing. Sidx reads b64 conflict-free; Swt reads b128 2-way (free).
//  No early return (barrier): q clamped, final store guarded.
// ---------------------------------------------------------------------------
#define QCHUNK 64
#define CHUNKS ((LQ + QCHUNK - 1) / QCHUNK)   // 306

__global__ __launch_bounds__(256) void ms_sample(
    const unsigned short* __restrict__ V0, const unsigned short* __restrict__ V1,
    const float* __restrict__ QS0, const float* __restrict__ QS1,
    const float* __restrict__ refp, unsigned short* __restrict__ Ocat)
{
    __shared__ unsigned short Sidx[16][64][4];  // [p][ql][corner] u16 row index
    __shared__ float          Swt [16][64][4];  // [p][ql][corner] fp32 weight

    const int b = blockIdx.x;
    const int h = b & 7;
    const int rest = b >> 3;               // (it*2+n)*CHUNKS + chunk
    const int chunk = rest % CHUNKS;
    const int inn   = rest / CHUNKS;       // it*2 + n
    const int n  = inn & 1;
    const int it = inn >> 1;

    const int tid = threadIdx.x;
    const int ql  = tid >> 2;              // 0..63 query slot
    const int lj  = tid & 3;               // phase1: level; phase2: dim quarter
    const int qraw = chunk * QCHUNK + ql;
    const bool valid = qraw < LQ;
    const int q  = valid ? qraw : LQ - 1;
    const int nq = n * LQ + q;

    const unsigned short* __restrict__ val = it ? V1 : V0;
    const float* __restrict__ QS = it ? QS1 : QS0;
    const unsigned short* __restrict__ vb2 =
        val + (size_t)(n * NHEADS + h) * LEN * HDIM;

    const int Hs[4] = {92, 46, 23, 12};
    const int Ws[4] = {160, 80, 40, 20};
    const int Ss[4] = {0, 14720, 18400, 19320};

    // ---- phase 1: this lane's level only ----
    {
        const int H = Hs[lj], W = Ws[lj], S = Ss[lj];
        const float* prow = QS + (size_t)nq * LDQS;
        const float4 o0 = *(const float4*)(prow + (h << 5) + lj * 8);
        const float4 o1 = *(const float4*)(prow + (h << 5) + lj * 8 + 4);
        const float4 a4 = *(const float4*)(prow + 256 + (h << 4) + lj * 4);
        const float2 rp = *(const float2*)(refp + (size_t)nq * 8 + lj * 2);
        const float fx = rp.x * (float)W - 0.5f;
        const float fy = rp.y * (float)H - 0.5f;
        const float oxs[4] = {o0.x, o0.z, o1.x, o1.z};
        const float oys[4] = {o0.y, o0.w, o1.y, o1.w};
        const float avs[4] = {a4.x, a4.y, a4.z, a4.w};
        #pragma unroll
        for (int k = 0; k < NPTS; k++) {
            const float x = fx + oxs[k];
            const float y = fy + oys[k];
            const float x0f = floorf(x), y0f = floorf(y);
            const int x0 = (int)x0f, y0 = (int)y0f;
            const float wx1 = x - x0f, wy1 = y - y0f;
            const float wx0 = 1.0f - wx1, wy0 = 1.0f - wy1;
            const int xc0 = min(max(x0, 0), W - 1);
            const int xc1 = min(max(x0 + 1, 0), W - 1);
            const int yc0 = min(max(y0, 0), H - 1);
            const int yc1 = min(max(y0 + 1, 0), H - 1);
            const float a = avs[k];
            const float ay0 = ((unsigned int)y0 < (unsigned int)H) ? a * wy0 : 0.f;
            const float ay1 = ((unsigned int)(y0 + 1) < (unsigned int)H) ? a * wy1 : 0.f;
            const float mx0 = ((unsigned int)x0 < (unsigned int)W) ? wx0 : 0.f;
            const float mx1 = ((unsigned int)(x0 + 1) < (unsigned int)W) ? wx1 : 0.f;
            const int r0 = S + yc0 * W, r1 = S + yc1 * W;
            union { uint2 u; unsigned short s4[4]; } ip;
            ip.s4[0] = (unsigned short)(r0 + xc0);
            ip.s4[1] = (unsigned short)(r0 + xc1);
            ip.s4[2] = (unsigned short)(r1 + xc0);
            ip.s4[3] = (unsigned short)(r1 + xc1);
            *(uint2*)&Sidx[lj * 4 + k][ql][0] = ip.u;
            float4 w4 = make_float4(ay0 * mx0, ay0 * mx1, ay1 * mx0, ay1 * mx1);
            *(float4*)&Swt[lj * 4 + k][ql][0] = w4;
        }
    }
    __syncthreads();

    // ---- phase 2: gather (layout identical to v3) ----
    const int dl = lj << 3;                // element offset 0,8,16,24
    const unsigned short* __restrict__ vdl = vb2 + dl;

    f32x2 acc[4];
    #pragma unroll
    for (int i = 0; i < 4; i++) acc[i] = (f32x2){0.f, 0.f};

    auto corner = [&](unsigned int eo, float wgt) {
        const uint4 c = *(const uint4*)(vdl + eo);
        const f32x2 w2 = {wgt, wgt};
        acc[0] += w2 * bfpair(c.x);
        acc[1] += w2 * bfpair(c.y);
        acc[2] += w2 * bfpair(c.z);
        acc[3] += w2 * bfpair(c.w);
    };

    #pragma unroll
    for (int p = 0; p < 16; p++) {
        const uint2 i2 = *(const uint2*)&Sidx[p][ql][0];
        const float4 w4 = *(const float4*)&Swt[p][ql][0];
        corner((i2.x & 0xFFFFu) << 5, w4.x);
        corner((i2.x >> 16) << 5, w4.y);
        corner((i2.y & 0xFFFFu) << 5, w4.z);
        corner((i2.y >> 16) << 5, w4.w);
    }

    if (valid) {
        union { uint4 u; unsigned short s[8]; } t;
        #pragma unroll
        for (int i = 0; i < 4; i++) {
            t.s[2 * i]     = f2bf(acc[i].x);
            t.s[2 * i + 1] = f2bf(acc[i].y);
        }
        *(uint4*)&Ocat[(size_t)nq * 512 + it * 256 + h * HDIM + dl] = t.u;
    }
}

// ---------------------------------------------------------------------------
extern "C" void kernel_launch(void* const* d_in, const int* in_sizes, int n_in,
                              void* d_out, int out_size, void* d_ws, size_t ws_size,
                              hipStream_t stream)
{
    const float* q0    = (const float*)d_in[0];
    const float* q1    = (const float*)d_in[1];
    const float* refp  = (const float*)d_in[2];
    const float* f0    = (const float*)d_in[3];
    const float* f1    = (const float*)d_in[4];
    const float* W_so  = (const float*)d_in[7];
    const float* b_so  = (const float*)d_in[8];
    const float* W_aw  = (const float*)d_in[9];
    const float* b_aw  = (const float*)d_in[10];
    const float* W_v   = (const float*)d_in[11];
    const float* b_v   = (const float*)d_in[12];
    const float* W_o   = (const float*)d_in[13];
    const float* b_o   = (const float*)d_in[14];
    const float* W_agg = (const float*)d_in[15];
    const float* b_agg = (const float*)d_in[16];
    float* out = (float*)d_out;

    float* ws = (float*)d_ws;
    float* QS0 = ws;                                        // NQ*384 fp32
    float* QS1 = QS0 + (size_t)NQ * LDQS;                   // NQ*384 fp32
    unsigned short* V0   = (unsigned short*)(QS1 + (size_t)NQ * LDQS);  // NQ*256 bf16
    unsigned short* V1   = V0 + (size_t)NQ * 256;
    unsigned short* Ocat = V1 + (size_t)NQ * 256;           // NQ*512 bf16
    unsigned short* Wvt    = Ocat + (size_t)NQ * 512;       // 65536
    unsigned short* Wsoawt = Wvt + 65536;                   // 98304
    unsigned short* Wfcat  = Wsoawt + 98304;                // 131072
    float* bsoaw = (float*)(Wfcat + 131072);                // 384
    float* bfus  = bsoaw + 384;                             // 256

    // bf16 A copies, zero extra workspace (lifetime-audited aliases):
    //  Qb0/Qb1 alias V0/V1   (q-GEMM reads them BEFORE value-GEMM writes V)
    //  Fb0/Fb1 alias Ocat    (value-GEMM reads them BEFORE ms_sample writes Ocat)
    unsigned short* Qb0 = V0;
    unsigned short* Qb1 = V1;
    unsigned short* Fb0 = Ocat;
    unsigned short* Fb1 = Ocat + (size_t)NQ * 256;

    const int MB = (NQ + 127) / 128;   // 306
    dim3 blk(256);

    // merged preprocessing: converts + weight prep + fused tail weights
    prep_all<<<20456, blk, 0, stream>>>(
        q0, q1, f0, f1, W_v, W_so, W_aw, b_so, b_aw, W_o, W_agg, b_o, b_agg,
        Qb0, Qb1, Fb0, Fb1, Wvt, Wsoawt, bsoaw, Wfcat, bfus);

    // q-side: offsets + logits for both iters (A = bf16 copies in V region)
    gemm_multi<<<dim3(3, MB, 2), blk, 0, stream>>>(
        Qb0, Qb1, Wsoawt, bsoaw, QS0, QS1, NQ, 256, 256, 384, LDQS, 0);

    joint_softmax<<<(NQ * NHEADS + 255) / 256, blk, 0, stream>>>(QS0, QS1);

    // values for both iters (A = bf16 copies in Ocat region), head-major scatter
    gemm_multi<<<dim3(2, MB, 2), blk, 0, stream>>>(
        Fb0, Fb1, Wvt, b_v, V0, V1, NQ, 256, 256, 256, 256, 2);

    // merged sampler (both iters) -> Ocat (overwrites Fb after value-GEMM)
    ms_sample<<<2 * 2 * CHUNKS * 8, blk, 0, stream>>>(V0, V1, QS0, QS1, refp, Ocat);

    // single K=512 tail GEMM -> out
    gemm_multi<<<dim3(2, MB, 1), blk, 0, stream>>>(
        Ocat, Ocat, Wfcat, bfus, out, out, NQ, 512, 512, 256, 256, 0);
}